// Round 3
// baseline (332.617 us; speedup 1.0000x reference)
//
#include <hip/hip_runtime.h>
#include <math.h>

// Problem constants
#define BB 16
#define EE 512
#define HH 512
#define VV 32000
#define LL 512
#define NQ 20
#define H2 1024   // 2H
#define H3 1536   // 3H
#define H4 2048   // 4H

// Workspace layout (float offsets; all 16B-aligned)
#define H0_OFF   0        // B*H   = 8192
#define GI_OFF   8192     // B*3H  = 24576
#define H_OFF    32768    // B*H   = 8192
#define UQ_OFF   40960    // B*2H  = 16384
#define E_OFF    57344    // B*L   = 8192
#define CTRL_OFF 65536    // 128 floats of control state
// ctrl indices (float/int):
#define BAR0_IDX 0
#define BAR1_IDX 16
#define BAR2_IDX 32
#define SE_IDX   64
#define SQ_IDX   80
#define WHD_IDX  96
#define ED_IDX   112

__device__ __forceinline__ float wave_reduce_add(float v) {
#pragma unroll
  for (int off = 32; off > 0; off >>= 1) v += __shfl_xor(v, off, 64);
  return v;
}

__device__ __forceinline__ float dot4(float4 a, float4 b) {
  return a.x * b.x + a.y * b.y + a.z * b.z + a.w * b.w;
}

// Device-scope grid barrier. Safe: grid=256 blocks x 512 thr, VGPR<256,
// LDS ~2KB -> every block resident on a distinct CU (256 CUs).
__device__ __forceinline__ void grid_bar(int* cnt) {
  __syncthreads();
  if (threadIdx.x == 0) {
    __threadfence();                 // release: our writes visible device-wide
    atomicAdd(cnt, 1);               // device-scope by default
    while (__hip_atomic_load(cnt, __ATOMIC_RELAXED, __HIP_MEMORY_SCOPE_AGENT) < 256)
      __builtin_amdgcn_s_sleep(8);
  }
  __syncthreads();
  __threadfence();                   // acquire: see other blocks' writes
}

__global__ void k_init(float* ctrl) {
  ctrl[threadIdx.x] = 0.f;           // <<<1,128>>> zeroes bars + Se/Sq/whd/ed
}

// Fused phases A-D. 256 blocks x 512 threads = 2048 waves.
__global__ __launch_bounds__(512) void k_fused(
    const int* __restrict__ y, const float* __restrict__ q,
    const float* __restrict__ qn, const float* __restrict__ g,
    const float* __restrict__ embed,
    const float* __restrict__ fc_w, const float* __restrict__ fc_b,
    const float* __restrict__ w_ih, const float* __restrict__ b_ih,
    const float* __restrict__ w_hh, const float* __restrict__ b_hh,
    const float* __restrict__ w_la, const float* __restrict__ wh_w,
    const float* __restrict__ wc_w, const float* __restrict__ wy_w,
    float* __restrict__ ws) {
  float* h0_ws = ws + H0_OFF;
  float* gi_ws = ws + GI_OFF;
  float* h_ws  = ws + H_OFF;
  float* uq_ws = ws + UQ_OFF;
  float* e_ws  = ws + E_OFF;
  float* ctrl  = ws + CTRL_OFF;
  int*   bar   = (int*)ctrl;

  __shared__ float s_lds[520];

  const int wv   = threadIdx.x >> 6;
  const int lane = threadIdx.x & 63;
  const int wid  = blockIdx.x * 8 + wv;   // 0..2047

  // ---------- Phase A: h0 (waves 0..511), gi (waves 512..2047) ----------
  if (wid < HH) {
    int j = wid;
    const float4* fw = (const float4*)(fc_w + (size_t)j * H4);
    float4 w[8];
#pragma unroll
    for (int it = 0; it < 8; ++it) w[it] = fw[it * 64 + lane];
    float acc[16];
#pragma unroll
    for (int b = 0; b < 16; ++b) {
      const float4* qn4 = (const float4*)(qn + (size_t)b * (NQ * H2));
      const float4* g4  = (const float4*)(g  + (size_t)b * (NQ * H2));
      float a = 0.f;
#pragma unroll
      for (int it = 0; it < 8; ++it) {
        int i4 = it * 64 + lane;
        float4 av = (i4 < 256) ? qn4[i4] : g4[i4 - 256];
        a += dot4(av, w[it]);
      }
      acc[b] = a;
    }
#pragma unroll
    for (int b = 0; b < 16; ++b) {
      float s = wave_reduce_add(acc[b]);
      if (lane == b) h0_ws[b * HH + j] = s + fc_b[j];
    }
  } else {
    int j = wid - HH;   // 0..1535
    const float4* wr = (const float4*)(w_ih + (size_t)j * EE);
    float4 w0 = wr[lane], w1 = wr[64 + lane];
    float acc[16];
#pragma unroll
    for (int b = 0; b < 16; ++b) {
      const float4* xr = (const float4*)(embed + (size_t)y[b] * EE);
      acc[b] = dot4(xr[lane], w0) + dot4(xr[64 + lane], w1);
    }
#pragma unroll
    for (int b = 0; b < 16; ++b) {
      float s = wave_reduce_add(acc[b]);
      if (lane == b) gi_ws[b * H3 + j] = s + b_ih[j];
    }
  }
  grid_bar(bar + BAR0_IDX);

  // ---------- Phase B: gh + GRU -> h  (waves 0..511, one j-triplet each) ----------
  if (wid < HH) {
    int j = wid;
    const float4* r0 = (const float4*)(w_hh + (size_t)j * HH);
    const float4* r1 = (const float4*)(w_hh + (size_t)(HH + j) * HH);
    const float4* r2 = (const float4*)(w_hh + (size_t)(2 * HH + j) * HH);
    float4 w0a = r0[lane], w0b = r0[64 + lane];
    float4 w1a = r1[lane], w1b = r1[64 + lane];
    float4 w2a = r2[lane], w2b = r2[64 + lane];
    float ar[16], az[16], an[16];
#pragma unroll
    for (int b = 0; b < 16; ++b) {
      const float4* hr = (const float4*)(h0_ws + b * HH);
      float4 a0 = hr[lane], a1 = hr[64 + lane];
      ar[b] = dot4(a0, w0a) + dot4(a1, w0b);
      az[b] = dot4(a0, w1a) + dot4(a1, w1b);
      an[b] = dot4(a0, w2a) + dot4(a1, w2b);
    }
#pragma unroll
    for (int b = 0; b < 16; ++b) {
      float sr = wave_reduce_add(ar[b]);
      float sz = wave_reduce_add(az[b]);
      float sn = wave_reduce_add(an[b]);
      if (lane == b) {
        const float* gi = gi_ws + b * H3;
        float r = 1.f / (1.f + expf(-(gi[j] + sr + b_hh[j])));
        float z = 1.f / (1.f + expf(-(gi[HH + j] + sz + b_hh[HH + j])));
        float n = tanhf(gi[2 * HH + j] + r * (sn + b_hh[2 * HH + j]));
        float h0v = h0_ws[b * HH + j];
        h_ws[b * HH + j] = (1.f - z) * n + z * h0v;
      }
    }
  }
  grid_bar(bar + BAR1_IDX);

  // ---------- Phase C: uq (all blocks; block=(b,dchunk), wave=K-slice) + whd/ed ----------
  {
    int cb = blockIdx.x >> 4;       // batch
    int dc = blockIdx.x & 15;       // 64-col chunk of uq
    const float* wp = w_la + (size_t)(wv * 64) * H2 + dc * 64 + lane;
    const float* hp = h_ws + cb * HH + wv * 64;
    float acc = 0.f;
#pragma unroll 8
    for (int k = 0; k < 64; ++k) acc += hp[k] * wp[(size_t)k * H2];

    if (dc == 0 && wv == 1) {       // whd[b] = h[b,:] . wh_w
      const float4* hr = (const float4*)(h_ws + cb * HH);
      const float4* wr = (const float4*)wh_w;
      float a = dot4(hr[lane], wr[lane]) + dot4(hr[64 + lane], wr[64 + lane]);
      a = wave_reduce_add(a);
      if (lane == 0) ctrl[WHD_IDX + cb] = a;
    }
    if (dc == 0 && wv == 2) {       // ed[b] = embed[y[b]] . wy_w
      const float4* xr = (const float4*)(embed + (size_t)y[cb] * EE);
      const float4* wr = (const float4*)wy_w;
      float a = dot4(xr[lane], wr[lane]) + dot4(xr[64 + lane], wr[64 + lane]);
      a = wave_reduce_add(a);
      if (lane == 0) ctrl[ED_IDX + cb] = a;
    }
    s_lds[wv * 64 + lane] = acc;
    __syncthreads();
    if (threadIdx.x < 64) {
      float s = 0.f;
#pragma unroll
      for (int i = 0; i < 8; ++i) s += s_lds[i * 64 + threadIdx.x];
      uq_ws[cb * H2 + dc * 64 + threadIdx.x] = s;
    }
  }
  grid_bar(bar + BAR2_IDX);

  // ---------- Phase D: score -> e=exp(s-20), partial Se/Sq ----------
  {
    int b  = wid >> 7;              // 128 waves per batch; block's 8 waves share b
    int lc = wid & 127;             // 4 l's per wave
    const float4* ur = (const float4*)(uq_ws + b * H2);
    const float4* wr = (const float4*)wc_w;
    float4 uqv[4], wcv[4];
#pragma unroll
    for (int it = 0; it < 4; ++it) { uqv[it] = ur[it * 64 + lane]; wcv[it] = wr[it * 64 + lane]; }
    float se = 0.f, sq = 0.f;
#pragma unroll
    for (int li = 0; li < 4; ++li) {
      int l = lc * 4 + li;
      const float4* qr = (const float4*)(q + (size_t)b * (NQ * LL * H2) + (size_t)l * H2);
      float a1 = 0.f, a2 = 0.f;
#pragma unroll
      for (int it = 0; it < 4; ++it) {
        float4 qv = qr[it * 64 + lane];
        a1 += dot4(qv, uqv[it]);
        a2 += dot4(qv, wcv[it]);
      }
      a1 = wave_reduce_add(a1);
      a2 = wave_reduce_add(a2);
      float e = expf(a1 - 20.f);    // constant shift: softmax invariant
      if (lane == 0) e_ws[b * LL + l] = e;
      se += e; sq += e * a2;
    }
    __syncthreads();                // reuse s_lds
    if (lane == 0) { s_lds[wv] = se; s_lds[8 + wv] = sq; }
    __syncthreads();
    if (threadIdx.x == 0) {
      float S1 = 0.f, S2 = 0.f;
#pragma unroll
      for (int i = 0; i < 8; ++i) { S1 += s_lds[i]; S2 += s_lds[8 + i]; }
      atomicAdd(ctrl + SE_IDX + b, S1);   // 16 blocks per b
      atomicAdd(ctrl + SQ_IDX + b, S2);
    }
  }
}

// Final: pre[b,v] = P_w[b,:] . fco_w[v,:] + fco_b[v],  P_w = pg[b] + alpha[b]*e
__global__ __launch_bounds__(256) void k_final(
    const float* __restrict__ ws, const float* __restrict__ fco_w,
    const float* __restrict__ fco_b, float* __restrict__ out) {
  const float* e_ws = ws + E_OFF;
  const float* ctrl = ws + CTRL_OFF;
  __shared__ float plds[16 * 516];
  __shared__ float s_pg[16], s_al[16];
  int tid = threadIdx.x;
  if (tid < 16) {
    float Se = ctrl[SE_IDX + tid], Sq = ctrl[SQ_IDX + tid];
    float p = ctrl[WHD_IDX + tid] + Sq / Se + ctrl[ED_IDX + tid];
    float pg = p > 0.f ? p : 0.2f * p;
    s_pg[tid] = pg;
    s_al[tid] = (1.f - pg) / Se;
  }
  __syncthreads();
#pragma unroll
  for (int it = 0; it < 8; ++it) {
    int i4 = it * 256 + tid;
    int row = i4 >> 7;              // batch
    int col = (i4 & 127) * 4;
    float4 v = ((const float4*)e_ws)[i4];
    float pg = s_pg[row], al = s_al[row];
    v.x = pg + al * v.x; v.y = pg + al * v.y;
    v.z = pg + al * v.z; v.w = pg + al * v.w;
    *(float4*)&plds[row * 516 + col] = v;
  }
  __syncthreads();
  int v = blockIdx.x * 16 + (tid & 15);
  int b = tid >> 4;
  const float4* fr = (const float4*)(fco_w + (size_t)v * LL);
  const float4* pr = (const float4*)&plds[b * 516];
  float acc = 0.f;
#pragma unroll 8
  for (int k4 = 0; k4 < 128; ++k4) {
    float4 f = fr[k4];
    float4 p = pr[k4];
    acc += f.x * p.x + f.y * p.y + f.z * p.z + f.w * p.w;
  }
  out[(size_t)b * VV + v] = acc + fco_b[v];
}

extern "C" void kernel_launch(void* const* d_in, const int* in_sizes, int n_in,
                              void* d_out, int out_size, void* d_ws, size_t ws_size,
                              hipStream_t stream) {
  const int*   y     = (const int*)d_in[0];
  const float* q     = (const float*)d_in[1];
  const float* qn    = (const float*)d_in[2];
  const float* g     = (const float*)d_in[3];
  const float* embed = (const float*)d_in[4];
  const float* fc_w  = (const float*)d_in[5];
  const float* fc_b  = (const float*)d_in[6];
  const float* w_ih  = (const float*)d_in[7];
  const float* w_hh  = (const float*)d_in[8];
  const float* b_ih  = (const float*)d_in[9];
  const float* b_hh  = (const float*)d_in[10];
  const float* w_la  = (const float*)d_in[12];
  const float* wh_w  = (const float*)d_in[15];
  const float* wc_w  = (const float*)d_in[16];
  const float* wy_w  = (const float*)d_in[17];
  const float* fco_w = (const float*)d_in[18];
  const float* fco_b = (const float*)d_in[19];
  float* ws  = (float*)d_ws;
  float* out = (float*)d_out;

  k_init<<<1, 128, 0, stream>>>(ws + CTRL_OFF);
  k_fused<<<256, 512, 0, stream>>>(y, q, qn, g, embed, fc_w, fc_b, w_ih, b_ih,
                                   w_hh, b_hh, w_la, wh_w, wc_w, wy_w, ws);
  k_final<<<2000, 256, 0, stream>>>(ws, fco_w, fco_b, out);
}

// Round 4
// 191.447 us; speedup vs baseline: 1.7374x; 1.7374x over previous
//
#include <hip/hip_runtime.h>
#include <math.h>

#define BB 16
#define EE 512
#define HH 512
#define VV 32000
#define LL 512
#define NQ 20
#define H2 1024   // 2H
#define H3 1536   // 3H
#define H4 2048   // 4H

// ws float offsets (all 16B aligned)
#define H0_OFF   0        // B*H    (uncached channel)
#define GI_OFF   8192     // B*3H   (uncached)
#define H_OFF    32768    // B*H    (uncached)
#define UQ_OFF   40960    // B*2H   (uncached)
#define E_OFF    57344    // B*L    (plain; crosses kernel boundary)
#define WHD_OFF  65536    // B      (plain)
#define ED_OFF   65552    // B      (plain)
#define PSE_OFF  65568    // 256 per-block partial Se (plain)
#define PSQ_OFF  65824    // 256 per-block partial Sq (plain)
#define FLAG_OFF 66080    // 3*256 uint tokens

#define TOKEN 0x13579BDFu

__device__ __forceinline__ float wave_reduce_add(float v) {
#pragma unroll
  for (int off = 32; off > 0; off >>= 1) v += __shfl_xor(v, off, 64);
  return v;
}
__device__ __forceinline__ float dot4(float4 a, float4 b) {
  return a.x * b.x + a.y * b.y + a.z * b.z + a.w * b.w;
}
// agent-scope (device-coherent) scalar channel — bypasses non-coherent L2
__device__ __forceinline__ void ustore(float* p, float v) {
  __hip_atomic_store(p, v, __ATOMIC_RELAXED, __HIP_MEMORY_SCOPE_AGENT);
}
__device__ __forceinline__ float uload(const float* p) {
  return __hip_atomic_load(p, __ATOMIC_RELAXED, __HIP_MEMORY_SCOPE_AGENT);
}

// Fence-free grid barrier: every wave drains its own stores (release), token
// per block, 256 threads poll 256 slots. No wbl2/inv. Replay-safe: stale
// tokens only relax the barrier, and all guarded data is value-deterministic.
__device__ __forceinline__ void flag_bar(unsigned* slots) {
  asm volatile("s_waitcnt vmcnt(0) lgkmcnt(0)" ::: "memory");
  __syncthreads();
  if (threadIdx.x == 0)
    __hip_atomic_store(&slots[blockIdx.x], TOKEN, __ATOMIC_RELAXED, __HIP_MEMORY_SCOPE_AGENT);
  if (threadIdx.x < 256) {
    while (__hip_atomic_load(&slots[threadIdx.x], __ATOMIC_RELAXED,
                             __HIP_MEMORY_SCOPE_AGENT) != TOKEN)
      __builtin_amdgcn_s_sleep(1);
  }
  __syncthreads();
}

// Fused phases A-D. 256 blocks x 512 threads (2048 waves, all co-resident:
// 8 waves/block, <=4 blocks/CU capacity at this size).
__global__ __launch_bounds__(512) void k_fused(
    const int* __restrict__ y, const float* __restrict__ q,
    const float* __restrict__ qn, const float* __restrict__ g,
    const float* __restrict__ embed,
    const float* __restrict__ fc_w, const float* __restrict__ fc_b,
    const float* __restrict__ w_ih, const float* __restrict__ b_ih,
    const float* __restrict__ w_hh, const float* __restrict__ b_hh,
    const float* __restrict__ w_la, const float* __restrict__ wh_w,
    const float* __restrict__ wc_w, const float* __restrict__ wy_w,
    float* __restrict__ ws) {
  float* h0_ws = ws + H0_OFF;
  float* gi_ws = ws + GI_OFF;
  float* h_ws  = ws + H_OFF;
  float* uq_ws = ws + UQ_OFF;
  float* e_ws  = ws + E_OFF;
  unsigned* flags = (unsigned*)(ws + FLAG_OFF);

  __shared__ float s_lds[520];
  const int wv   = threadIdx.x >> 6;
  const int lane = threadIdx.x & 63;
  float h0_local = 0.f;   // lane b of waves wv<2 keeps h0[b, j] for phase B

  // -------- Phase A: every block = 2 h0-waves + 6 gi-waves (balanced) -----
  if (wv < 2) {
    int j = blockIdx.x * 2 + wv;                 // 0..511
    const float4* fw = (const float4*)(fc_w + (size_t)j * H4);
    float4 w[8];
#pragma unroll
    for (int it = 0; it < 8; ++it) w[it] = fw[it * 64 + lane];
    float acc[16];
#pragma unroll
    for (int b = 0; b < 16; ++b) {
      const float4* qn4 = (const float4*)(qn + (size_t)b * (NQ * H2));
      const float4* g4  = (const float4*)(g  + (size_t)b * (NQ * H2));
      float a = 0.f;
#pragma unroll
      for (int it = 0; it < 4; ++it) a += dot4(qn4[it * 64 + lane], w[it]);
#pragma unroll
      for (int it = 4; it < 8; ++it) a += dot4(g4[(it - 4) * 64 + lane], w[it]);
      acc[b] = a;
    }
#pragma unroll
    for (int b = 0; b < 16; ++b) {
      float s = wave_reduce_add(acc[b]);
      if (lane == b) { h0_local = s + fc_b[j]; ustore(&h0_ws[b * HH + j], h0_local); }
    }
  } else {
    int j = blockIdx.x * 6 + (wv - 2);           // 0..1535
    const float4* wr = (const float4*)(w_ih + (size_t)j * EE);
    float4 w0 = wr[lane], w1 = wr[64 + lane];
    float acc[16];
#pragma unroll
    for (int b = 0; b < 16; ++b) {
      const float4* xr = (const float4*)(embed + (size_t)y[b] * EE);
      acc[b] = dot4(xr[lane], w0) + dot4(xr[64 + lane], w1);
    }
#pragma unroll
    for (int b = 0; b < 16; ++b) {
      float s = wave_reduce_add(acc[b]);
      if (lane == b) ustore(&gi_ws[b * H3 + j], s + b_ih[j]);
    }
  }
  flag_bar(flags);

  // -------- Phase B: gh + GRU -> h (waves wv<2, same j as phase A) --------
  if (wv < 2) {
    int j = blockIdx.x * 2 + wv;
    const float4* r0 = (const float4*)(w_hh + (size_t)j * HH);
    const float4* r1 = (const float4*)(w_hh + (size_t)(HH + j) * HH);
    const float4* r2 = (const float4*)(w_hh + (size_t)(2 * HH + j) * HH);
    float4 w0a = r0[lane], w0b = r0[64 + lane];
    float4 w1a = r1[lane], w1b = r1[64 + lane];
    float4 w2a = r2[lane], w2b = r2[64 + lane];
    float m_sr = 0.f, m_sz = 0.f, m_sn = 0.f;
#pragma unroll
    for (int b = 0; b < 16; ++b) {
      const float* h0b = h0_ws + b * HH;
      float4 a0, a1;
      a0.x = uload(&h0b[lane * 4 + 0]); a0.y = uload(&h0b[lane * 4 + 1]);
      a0.z = uload(&h0b[lane * 4 + 2]); a0.w = uload(&h0b[lane * 4 + 3]);
      a1.x = uload(&h0b[256 + lane * 4 + 0]); a1.y = uload(&h0b[256 + lane * 4 + 1]);
      a1.z = uload(&h0b[256 + lane * 4 + 2]); a1.w = uload(&h0b[256 + lane * 4 + 3]);
      float ar = dot4(a0, w0a) + dot4(a1, w0b);
      float az = dot4(a0, w1a) + dot4(a1, w1b);
      float an = dot4(a0, w2a) + dot4(a1, w2b);
      ar = wave_reduce_add(ar); az = wave_reduce_add(az); an = wave_reduce_add(an);
      if (lane == b) { m_sr = ar; m_sz = az; m_sn = an; }
    }
    if (lane < 16) {
      int b = lane;
      float gi0 = uload(&gi_ws[b * H3 + j]);
      float gi1 = uload(&gi_ws[b * H3 + HH + j]);
      float gi2 = uload(&gi_ws[b * H3 + 2 * HH + j]);
      float r = 1.f / (1.f + expf(-(gi0 + m_sr + b_hh[j])));
      float z = 1.f / (1.f + expf(-(gi1 + m_sz + b_hh[HH + j])));
      float n = tanhf(gi2 + r * (m_sn + b_hh[2 * HH + j]));
      ustore(&h_ws[b * HH + j], (1.f - z) * n + z * h0_local);
    }
  }
  flag_bar(flags + 256);

  // -------- Phase C: uq[b,:] (block=(b,dchunk), wave=K-slice) + whd/ed ----
  {
    int cb = blockIdx.x >> 4;       // batch
    int dc = blockIdx.x & 15;       // 64-col chunk
    const float* wp    = w_la + (size_t)(wv * 64) * H2 + dc * 64 + lane;
    const float* hbase = h_ws + cb * HH + wv * 64;
    float acc = 0.f;
#pragma unroll 8
    for (int k = 0; k < 64; ++k) acc += uload(&hbase[k]) * wp[(size_t)k * H2];

    if (dc == 0 && wv == 1) {       // whd[b] = h[b,:].wh_w
      float a = 0.f;
#pragma unroll
      for (int e = 0; e < 4; ++e) {
        a += uload(&h_ws[cb * HH + lane * 4 + e]) * wh_w[lane * 4 + e];
        a += uload(&h_ws[cb * HH + 256 + lane * 4 + e]) * wh_w[256 + lane * 4 + e];
      }
      a = wave_reduce_add(a);
      if (lane == 0) ws[WHD_OFF + cb] = a;
    }
    if (dc == 0 && wv == 2) {       // ed[b] = embed[y[b]].wy_w
      const float4* xr = (const float4*)(embed + (size_t)y[cb] * EE);
      const float4* wr = (const float4*)wy_w;
      float a = dot4(xr[lane], wr[lane]) + dot4(xr[64 + lane], wr[64 + lane]);
      a = wave_reduce_add(a);
      if (lane == 0) ws[ED_OFF + cb] = a;
    }
    s_lds[wv * 64 + lane] = acc;
    __syncthreads();
    if (threadIdx.x < 64) {
      float s = 0.f;
#pragma unroll
      for (int i = 0; i < 8; ++i) s += s_lds[i * 64 + threadIdx.x];
      ustore(&uq_ws[cb * H2 + dc * 64 + threadIdx.x], s);
    }
  }
  flag_bar(flags + 512);

  // -------- Phase D: score -> e = exp(s-20); per-block partial Se/Sq ------
  {
    int b  = blockIdx.x >> 4;
    int lc = (blockIdx.x & 15) * 8 + wv;         // 0..127, 4 l's per wave
    const float* uqb = uq_ws + b * H2;
    const float4* wr = (const float4*)wc_w;
    float4 uqv[4], wcv[4];
#pragma unroll
    for (int it = 0; it < 4; ++it) {
      int fi = (it * 64 + lane) * 4;
      uqv[it].x = uload(&uqb[fi]);     uqv[it].y = uload(&uqb[fi + 1]);
      uqv[it].z = uload(&uqb[fi + 2]); uqv[it].w = uload(&uqb[fi + 3]);
      wcv[it] = wr[it * 64 + lane];
    }
    float se = 0.f, sq = 0.f;
#pragma unroll
    for (int li = 0; li < 4; ++li) {
      int l = lc * 4 + li;
      const float4* qr = (const float4*)(q + (size_t)b * (NQ * LL * H2) + (size_t)l * H2);
      float a1 = 0.f, a2 = 0.f;
#pragma unroll
      for (int it = 0; it < 4; ++it) {
        float4 qv = qr[it * 64 + lane];
        a1 += dot4(qv, uqv[it]);
        a2 += dot4(qv, wcv[it]);
      }
      a1 = wave_reduce_add(a1);
      a2 = wave_reduce_add(a2);
      float e = expf(a1 - 20.f);      // constant shift: softmax-invariant
      if (lane == 0) e_ws[b * LL + l] = e;
      se += e; sq += e * a2;
    }
    __syncthreads();                  // s_lds reuse
    if (lane == 0) { s_lds[wv] = se; s_lds[8 + wv] = sq; }
    __syncthreads();
    if (threadIdx.x == 0) {
      float S1 = 0.f, S2 = 0.f;
#pragma unroll
      for (int i = 0; i < 8; ++i) { S1 += s_lds[i]; S2 += s_lds[8 + i]; }
      ws[PSE_OFF + blockIdx.x] = S1;  // plain per-block slot (no atomics)
      ws[PSQ_OFF + blockIdx.x] = S2;
    }
  }
}

// Final: pre[b,v] = P_w[b,:].fco_w[v,:] + fco_b[v],  P_w = pg[b] + al[b]*e
__global__ __launch_bounds__(256) void k_final(
    const float* __restrict__ ws, const float* __restrict__ fco_w,
    const float* __restrict__ fco_b, float* __restrict__ out) {
  const float* e_ws = ws + E_OFF;
  __shared__ float plds[16 * 516];
  __shared__ float s_pg[16], s_al[16];
  int tid = threadIdx.x;
  if (tid < 16) {
    float Se = 0.f, Sq = 0.f;
#pragma unroll
    for (int i = 0; i < 16; ++i) {
      Se += ws[PSE_OFF + tid * 16 + i];
      Sq += ws[PSQ_OFF + tid * 16 + i];
    }
    float p = ws[WHD_OFF + tid] + Sq / Se + ws[ED_OFF + tid];
    float pg = p > 0.f ? p : 0.2f * p;
    s_pg[tid] = pg;
    s_al[tid] = (1.f - pg) / Se;
  }
  __syncthreads();
#pragma unroll
  for (int it = 0; it < 8; ++it) {
    int i4 = it * 256 + tid;
    int row = i4 >> 7;
    int col = (i4 & 127) * 4;
    float4 v = ((const float4*)e_ws)[i4];
    float pg = s_pg[row], al = s_al[row];
    v.x = pg + al * v.x; v.y = pg + al * v.y;
    v.z = pg + al * v.z; v.w = pg + al * v.w;
    *(float4*)&plds[row * 516 + col] = v;
  }
  __syncthreads();
  int v = blockIdx.x * 16 + (tid & 15);
  int b = tid >> 4;
  const float4* fr = (const float4*)(fco_w + (size_t)v * LL);
  const float4* pr = (const float4*)&plds[b * 516];
  float acc = 0.f;
#pragma unroll 8
  for (int k4 = 0; k4 < 128; ++k4) {
    float4 f = fr[k4];
    float4 p = pr[k4];
    acc += f.x * p.x + f.y * p.y + f.z * p.z + f.w * p.w;
  }
  out[(size_t)b * VV + v] = acc + fco_b[v];
}

extern "C" void kernel_launch(void* const* d_in, const int* in_sizes, int n_in,
                              void* d_out, int out_size, void* d_ws, size_t ws_size,
                              hipStream_t stream) {
  const int*   y     = (const int*)d_in[0];
  const float* q     = (const float*)d_in[1];
  const float* qn    = (const float*)d_in[2];
  const float* g     = (const float*)d_in[3];
  const float* embed = (const float*)d_in[4];
  const float* fc_w  = (const float*)d_in[5];
  const float* fc_b  = (const float*)d_in[6];
  const float* w_ih  = (const float*)d_in[7];
  const float* w_hh  = (const float*)d_in[8];
  const float* b_ih  = (const float*)d_in[9];
  const float* b_hh  = (const float*)d_in[10];
  const float* w_la  = (const float*)d_in[12];
  const float* wh_w  = (const float*)d_in[15];
  const float* wc_w  = (const float*)d_in[16];
  const float* wy_w  = (const float*)d_in[17];
  const float* fco_w = (const float*)d_in[18];
  const float* fco_b = (const float*)d_in[19];
  float* ws  = (float*)d_ws;
  float* out = (float*)d_out;

  k_fused<<<256, 512, 0, stream>>>(y, q, qn, g, embed, fc_w, fc_b, w_ih, b_ih,
                                   w_hh, b_hh, w_la, wh_w, wc_w, wy_w, ws);
  k_final<<<2000, 256, 0, stream>>>(ws, fco_w, fco_b, out);
}

// Round 5
// 159.199 us; speedup vs baseline: 2.0893x; 1.2026x over previous
//
#include <hip/hip_runtime.h>
#include <math.h>

#define BB 16
#define EE 512
#define HH 512
#define VV 32000
#define LL 512
#define NQ 20
#define H2 1024   // 2H
#define H3 1536   // 3H
#define H4 2048   // 4H

// ws float offsets (16B aligned)
#define H0_OFF   0        // B*H   = 8192
#define GI_OFF   8192     // B*3H  = 24576
#define H_OFF    32768    // B*H   = 8192
#define UQ_OFF   40960    // B*2H  = 16384
#define E_OFF    57344    // B*L   = 8192
#define WHD_OFF  65536    // B
#define ED_OFF   65552    // B
#define PSE_OFF  65568    // 2048 per-block partial Se
#define PSQ_OFF  67616    // 2048 per-block partial Sq

__device__ __forceinline__ float wave_reduce_add(float v) {
#pragma unroll
  for (int off = 32; off > 0; off >>= 1) v += __shfl_xor(v, off, 64);
  return v;
}
__device__ __forceinline__ float dot4(float4 a, float4 b) {
  return a.x * b.x + a.y * b.y + a.z * b.z + a.w * b.w;
}

// K1: wave per output column; all 16 b in registers. Weights read once.
//   waves [0,512):    h0[b,j] = concat([qn_t,g_t][b]) . fc_w[j,:] + fc_b[j]
//   waves [512,2048): gi[b,j'] = embed[y[b]] . w_ih[j',:] + b_ih[j']
__global__ __launch_bounds__(256) void k_in_gemm(
    const int* __restrict__ y, const float* __restrict__ qn, const float* __restrict__ g,
    const float* __restrict__ embed,
    const float* __restrict__ fc_w, const float* __restrict__ fc_b,
    const float* __restrict__ w_ih, const float* __restrict__ b_ih,
    float* __restrict__ h0_ws, float* __restrict__ gi_ws) {
  int gw = (blockIdx.x * 256 + threadIdx.x) >> 6;   // 0..2047
  int lane = threadIdx.x & 63;
  if (gw < HH) {
    int j = gw;
    const float4* fw = (const float4*)(fc_w + (size_t)j * H4);
    float4 w[8];
#pragma unroll
    for (int it = 0; it < 8; ++it) w[it] = fw[it * 64 + lane];
    float acc[16];
#pragma unroll
    for (int b = 0; b < 16; ++b) {
      const float4* qn4 = (const float4*)(qn + (size_t)b * (NQ * H2));
      const float4* g4  = (const float4*)(g  + (size_t)b * (NQ * H2));
      float a = 0.f;
#pragma unroll
      for (int it = 0; it < 4; ++it) a += dot4(qn4[it * 64 + lane], w[it]);
#pragma unroll
      for (int it = 4; it < 8; ++it) a += dot4(g4[(it - 4) * 64 + lane], w[it]);
      acc[b] = a;
    }
#pragma unroll
    for (int b = 0; b < 16; ++b) {
      float s = wave_reduce_add(acc[b]);
      if (lane == b) h0_ws[b * HH + j] = s + fc_b[j];
    }
  } else {
    int j = gw - HH;   // 0..1535
    const float4* wr = (const float4*)(w_ih + (size_t)j * EE);
    float4 w0 = wr[lane], w1 = wr[64 + lane];
    float acc[16];
#pragma unroll
    for (int b = 0; b < 16; ++b) {
      const float4* xr = (const float4*)(embed + (size_t)y[b] * EE);
      acc[b] = dot4(xr[lane], w0) + dot4(xr[64 + lane], w1);
    }
#pragma unroll
    for (int b = 0; b < 16; ++b) {
      float s = wave_reduce_add(acc[b]);
      if (lane == b) gi_ws[b * H3 + j] = s + b_ih[j];
    }
  }
}

// K2: gh + GRU fused. Wave j loads the 3 w_hh rows (r,z,n); loops b;
// lane<16 computes gates and writes h[b,j].
__global__ __launch_bounds__(256) void k_gh_gru(
    const float* __restrict__ h0_ws, const float* __restrict__ gi_ws,
    const float* __restrict__ w_hh, const float* __restrict__ b_hh,
    float* __restrict__ h_ws) {
  int wv = threadIdx.x >> 6, lane = threadIdx.x & 63;
  int j = blockIdx.x * 4 + wv;   // 0..511
  const float4* r0 = (const float4*)(w_hh + (size_t)j * HH);
  const float4* r1 = (const float4*)(w_hh + (size_t)(HH + j) * HH);
  const float4* r2 = (const float4*)(w_hh + (size_t)(2 * HH + j) * HH);
  float4 w0a = r0[lane], w0b = r0[64 + lane];
  float4 w1a = r1[lane], w1b = r1[64 + lane];
  float4 w2a = r2[lane], w2b = r2[64 + lane];
  float m_sr = 0.f, m_sz = 0.f, m_sn = 0.f;
#pragma unroll
  for (int b = 0; b < 16; ++b) {
    const float4* hr = (const float4*)(h0_ws + b * HH);
    float4 a0 = hr[lane], a1 = hr[64 + lane];
    float ar = dot4(a0, w0a) + dot4(a1, w0b);
    float az = dot4(a0, w1a) + dot4(a1, w1b);
    float an = dot4(a0, w2a) + dot4(a1, w2b);
    ar = wave_reduce_add(ar); az = wave_reduce_add(az); an = wave_reduce_add(an);
    if (lane == b) { m_sr = ar; m_sz = az; m_sn = an; }
  }
  if (lane < 16) {
    int b = lane;
    const float* gi = gi_ws + b * H3;
    float r = 1.f / (1.f + expf(-(gi[j] + m_sr + b_hh[j])));
    float z = 1.f / (1.f + expf(-(gi[HH + j] + m_sz + b_hh[HH + j])));
    float n = tanhf(gi[2 * HH + j] + r * (m_sn + b_hh[2 * HH + j]));
    float h0v = h0_ws[b * HH + j];
    h_ws[b * HH + j] = (1.f - z) * n + z * h0v;
  }
}

// K3: uq[b,:] = h[b,:] @ w_la  (block=(b,dchunk), 8-wave K-split) + whd/ed
__global__ __launch_bounds__(512) void k_uq(
    const int* __restrict__ y, const float* __restrict__ embed,
    const float* __restrict__ h_ws, const float* __restrict__ w_la,
    const float* __restrict__ wh_w, const float* __restrict__ wy_w,
    float* __restrict__ uq_ws, float* __restrict__ whd_ws, float* __restrict__ ed_ws) {
  __shared__ float s_lds[512];
  int wv = threadIdx.x >> 6, lane = threadIdx.x & 63;
  int cb = blockIdx.x >> 4;       // batch
  int dc = blockIdx.x & 15;       // 64-col chunk
  const float* wp = w_la + (size_t)(wv * 64) * H2 + dc * 64 + lane;
  const float* hp = h_ws + cb * HH + wv * 64;
  float acc = 0.f;
#pragma unroll 8
  for (int k = 0; k < 64; ++k) acc += hp[k] * wp[(size_t)k * H2];

  if (dc == 0 && wv == 1) {       // whd[b] = h[b,:].wh_w
    const float4* hr = (const float4*)(h_ws + cb * HH);
    const float4* wr = (const float4*)wh_w;
    float a = dot4(hr[lane], wr[lane]) + dot4(hr[64 + lane], wr[64 + lane]);
    a = wave_reduce_add(a);
    if (lane == 0) whd_ws[cb] = a;
  }
  if (dc == 0 && wv == 2) {       // ed[b] = embed[y[b]].wy_w
    const float4* xr = (const float4*)(embed + (size_t)y[cb] * EE);
    const float4* wr = (const float4*)wy_w;
    float a = dot4(xr[lane], wr[lane]) + dot4(xr[64 + lane], wr[64 + lane]);
    a = wave_reduce_add(a);
    if (lane == 0) ed_ws[cb] = a;
  }
  s_lds[wv * 64 + lane] = acc;
  __syncthreads();
  if (threadIdx.x < 64) {
    float s = 0.f;
#pragma unroll
    for (int i = 0; i < 8; ++i) s += s_lds[i * 64 + threadIdx.x];
    uq_ws[cb * H2 + dc * 64 + threadIdx.x] = s;
  }
}

// K4: score -> e = exp(s-20) + per-block partial Se/Sq (no atomics).
// 2048 blocks x 4 waves; wave = one (b,l); 128 blocks per b.
__global__ __launch_bounds__(256) void k_score(
    const float* __restrict__ q, const float* __restrict__ uq_ws,
    const float* __restrict__ wc_w,
    float* __restrict__ e_ws, float* __restrict__ pse_ws, float* __restrict__ psq_ws) {
  __shared__ float s_se[4], s_sq[4];
  int wv = threadIdx.x >> 6, lane = threadIdx.x & 63;
  int gw = blockIdx.x * 4 + wv;
  int b = gw >> 9, l = gw & (LL - 1);
  const float4* qr = (const float4*)(q + (size_t)b * (NQ * LL * H2) + (size_t)l * H2);
  const float4* ur = (const float4*)(uq_ws + b * H2);
  const float4* wr = (const float4*)wc_w;
  float a1 = 0.f, a2 = 0.f;
#pragma unroll
  for (int it = 0; it < 4; ++it) {
    float4 qv = qr[it * 64 + lane];
    a1 += dot4(qv, ur[it * 64 + lane]);
    a2 += dot4(qv, wr[it * 64 + lane]);
  }
  a1 = wave_reduce_add(a1);
  a2 = wave_reduce_add(a2);
  float e = expf(a1 - 20.f);      // constant shift: softmax-invariant
  if (lane == 0) {
    e_ws[b * LL + l] = e;
    s_se[wv] = e;
    s_sq[wv] = e * a2;
  }
  __syncthreads();
  if (threadIdx.x == 0) {
    pse_ws[blockIdx.x] = s_se[0] + s_se[1] + s_se[2] + s_se[3];
    psq_ws[blockIdx.x] = s_sq[0] + s_sq[1] + s_sq[2] + s_sq[3];
  }
}

// K5: softmax finalize (reduce 128 partials per b) + P_w affine + final GEMM.
__global__ __launch_bounds__(256) void k_final(
    const float* __restrict__ ws, const float* __restrict__ fco_w,
    const float* __restrict__ fco_b, float* __restrict__ out) {
  const float* e_ws = ws + E_OFF;
  __shared__ float plds[16 * 516];
  __shared__ float sred_e[256], sred_q[256];
  __shared__ float s_pg[16], s_al[16];
  int tid = threadIdx.x;
  {                                // b = tid>>4, i = tid&15: sum 8 slots each
    int b = tid >> 4, i = tid & 15;
    float se = 0.f, sq = 0.f;
#pragma unroll
    for (int k = 0; k < 8; ++k) {
      se += ws[PSE_OFF + b * 128 + i * 8 + k];
      sq += ws[PSQ_OFF + b * 128 + i * 8 + k];
    }
    sred_e[tid] = se; sred_q[tid] = sq;
  }
  __syncthreads();
  if (tid < 16) {
    float Se = 0.f, Sq = 0.f;
#pragma unroll
    for (int i = 0; i < 16; ++i) { Se += sred_e[tid * 16 + i]; Sq += sred_q[tid * 16 + i]; }
    float p = ws[WHD_OFF + tid] + Sq / Se + ws[ED_OFF + tid];
    float pg = p > 0.f ? p : 0.2f * p;
    s_pg[tid] = pg;
    s_al[tid] = (1.f - pg) / Se;
  }
  __syncthreads();
#pragma unroll
  for (int it = 0; it < 8; ++it) {
    int i4 = it * 256 + tid;
    int row = i4 >> 7;
    int col = (i4 & 127) * 4;
    float4 v = ((const float4*)e_ws)[i4];
    float pg = s_pg[row], al = s_al[row];
    v.x = pg + al * v.x; v.y = pg + al * v.y;
    v.z = pg + al * v.z; v.w = pg + al * v.w;
    *(float4*)&plds[row * 516 + col] = v;
  }
  __syncthreads();
  int v = blockIdx.x * 16 + (tid & 15);
  int b = tid >> 4;
  const float4* fr = (const float4*)(fco_w + (size_t)v * LL);
  const float4* pr = (const float4*)&plds[b * 516];
  float acc = 0.f;
#pragma unroll 8
  for (int k4 = 0; k4 < 128; ++k4) {
    float4 f = fr[k4];
    float4 p = pr[k4];
    acc += f.x * p.x + f.y * p.y + f.z * p.z + f.w * p.w;
  }
  out[(size_t)b * VV + v] = acc + fco_b[v];
}

extern "C" void kernel_launch(void* const* d_in, const int* in_sizes, int n_in,
                              void* d_out, int out_size, void* d_ws, size_t ws_size,
                              hipStream_t stream) {
  const int*   y     = (const int*)d_in[0];
  const float* q     = (const float*)d_in[1];
  const float* qn    = (const float*)d_in[2];
  const float* g     = (const float*)d_in[3];
  const float* embed = (const float*)d_in[4];
  const float* fc_w  = (const float*)d_in[5];
  const float* fc_b  = (const float*)d_in[6];
  const float* w_ih  = (const float*)d_in[7];
  const float* w_hh  = (const float*)d_in[8];
  const float* b_ih  = (const float*)d_in[9];
  const float* b_hh  = (const float*)d_in[10];
  const float* w_la  = (const float*)d_in[12];
  const float* wh_w  = (const float*)d_in[15];
  const float* wc_w  = (const float*)d_in[16];
  const float* wy_w  = (const float*)d_in[17];
  const float* fco_w = (const float*)d_in[18];
  const float* fco_b = (const float*)d_in[19];
  float* ws  = (float*)d_ws;
  float* out = (float*)d_out;

  k_in_gemm<<<512, 256, 0, stream>>>(y, qn, g, embed, fc_w, fc_b, w_ih, b_ih,
                                     ws + H0_OFF, ws + GI_OFF);
  k_gh_gru<<<128, 256, 0, stream>>>(ws + H0_OFF, ws + GI_OFF, w_hh, b_hh,
                                    ws + H_OFF);
  k_uq<<<256, 512, 0, stream>>>(y, embed, ws + H_OFF, w_la, wh_w, wy_w,
                                ws + UQ_OFF, ws + WHD_OFF, ws + ED_OFF);
  k_score<<<2048, 256, 0, stream>>>(q, ws + UQ_OFF, wc_w,
                                    ws + E_OFF, ws + PSE_OFF, ws + PSQ_OFF);
  k_final<<<2000, 256, 0, stream>>>(ws, fco_w, fco_b, out);
}